// Round 16
// baseline (415.592 us; speedup 1.0000x reference)
//
#include <hip/hip_runtime.h>
#include <stdint.h>

#define NN 100000
#define NE 1600000
#define NMASKW 400000   // (NN*128)/32 mask words per layer
#define NRANGE 4
#define RSZ 25000       // NN / NRANGE
#define NCHUNK 64
#define ECHUNK 25000    // NE / NCHUNK

typedef float f4 __attribute__((ext_vector_type(4)));
typedef float f2 __attribute__((ext_vector_type(2)));
typedef unsigned short us4 __attribute__((ext_vector_type(4)));
typedef short s16x8 __attribute__((ext_vector_type(8)));

__device__ inline float bf2f(unsigned short u) {
  return __uint_as_float(((uint32_t)u) << 16);
}
__device__ inline unsigned short f2bf(float f) {  // round-to-nearest-even
  uint32_t u = __float_as_uint(f);
  return (unsigned short)((u + 0x7fffu + ((u >> 16) & 1u)) >> 16);
}
__device__ inline float lo16(uint32_t q) { return __uint_as_float(q << 16); }
__device__ inline float hi16(uint32_t q) { return __uint_as_float(q & 0xffff0000u); }

// Threefry-2x32, 20 rounds (Random123 / JAX exact).
__host__ __device__ inline void threefry2x32(uint32_t k0, uint32_t k1,
                                             uint32_t x0, uint32_t x1,
                                             uint32_t* y0, uint32_t* y1) {
  uint32_t ks[3] = {k0, k1, k0 ^ k1 ^ 0x1BD11BDAu};
  x0 += ks[0]; x1 += ks[1];
  const uint32_t R[2][4] = {{13u, 15u, 26u, 6u}, {17u, 29u, 16u, 24u}};
#pragma unroll
  for (int i = 0; i < 5; ++i) {
#pragma unroll
    for (int j = 0; j < 4; ++j) {
      uint32_t r = R[i & 1][j];
      x0 += x1;
      x1 = (x1 << r) | (x1 >> (32u - r));
      x1 ^= x0;
    }
    x0 += ks[(i + 1) % 3];
    x1 += ks[(i + 2) % 3] + (uint32_t)(i + 1);
  }
  *y0 = x0; *y1 = x1;
}

__device__ inline uint32_t tf_bits32(uint32_t k0, uint32_t k1, uint32_t idx) {
  uint32_t a, b;
  threefry2x32(k0, k1, 0u, idx, &a, &b);
  return a ^ b;
}

// Merged preprocessing: LDS-private histogram blocks INTERLEAVED with
// mask/wsplit blocks (even/odd for b<512) so each CU co-hosts one
// memory-bound hist block and one VALU-bound mask block -> pipe overlap.
// hist: 256 jobs. maskw: 396 jobs (5 wsplit + 391 mask). Grid 652 x 1024.
__global__ __launch_bounds__(1024) void k_pre(
    const int* __restrict__ ei, unsigned short* __restrict__ hc,
    uint32_t* __restrict__ m1, uint32_t* __restrict__ m2,
    uint32_t k10, uint32_t k11, uint32_t k20, uint32_t k21,
    const float* __restrict__ W1, const float* __restrict__ W2,
    const float* __restrict__ W3,
    unsigned short* __restrict__ w1h, unsigned short* __restrict__ w1l,
    unsigned short* __restrict__ w2h, unsigned short* __restrict__ w2l,
    unsigned short* __restrict__ w3h, unsigned short* __restrict__ w3l) {
  __shared__ uint32_t h[RSZ / 2];  // 50 KB (hist blocks only)
  int b = blockIdx.x;
  bool isHist;
  int job;
  if (b < 512) { isHist = !(b & 1); job = b >> 1; }
  else         { isHist = false;    job = 256 + (b - 512); }

  if (isHist) {
    const int r = job & (NRANGE - 1);
    const int c = job >> 2;
    const int lo = r * RSZ;
    for (int i = threadIdx.x; i < RSZ / 2; i += 1024) h[i] = 0u;
    __syncthreads();
    const int* dp = ei + NE + c * ECHUNK;
    for (int i = threadIdx.x * 4; i < ECHUNK; i += 4096) {
      int4 d4 = *(const int4*)(dp + i);
#define CNT(dd)                                                           \
      {                                                                   \
        uint32_t x = (uint32_t)((dd) - lo);                               \
        if (x < (uint32_t)RSZ)                                            \
          atomicAdd(&h[x >> 1], (x & 1u) ? 0x10000u : 1u);                \
      }
      CNT(d4.x); CNT(d4.y); CNT(d4.z); CNT(d4.w);
#undef CNT
    }
    __syncthreads();
    uint32_t* dst = (uint32_t*)(hc + (size_t)c * NN + lo);
    for (int i = threadIdx.x; i < RSZ / 2; i += 1024) dst[i] = h[i];
  } else if (job < 5) {
    // wsplit: 80 wave-jobs, 16 per block.
    int bb = job * 16 + (threadIdx.x >> 6);
    int lane = threadIdx.x & 63;
    const float* W; unsigned short *H, *L; int dout, j0;
    if (bb < 32)      { W = W1; H = w1h; L = w1l; dout = 128; j0 = bb; }
    else if (bb < 64) { W = W2; H = w2h; L = w2l; dout = 128; j0 = bb - 32; }
    else              { W = W3; H = w3h; L = w3l; dout = 64;  j0 = bb - 64; }
    int kk = j0 & 3;
    int ct = j0 >> 2;
    int kbase = kk * 32 + (lane >> 4) * 8;
    int col = ct * 16 + (lane & 15);
    us4 h0, h1, l0, l1;
#pragma unroll
    for (int j = 0; j < 4; ++j) {
      float v = W[(size_t)(kbase + j) * dout + col];
      h0[j] = f2bf(v);
      l0[j] = f2bf(v - bf2f(h0[j]));
      float v2 = W[(size_t)(kbase + 4 + j) * dout + col];
      h1[j] = f2bf(v2);
      l1[j] = f2bf(v2 - bf2f(h1[j]));
    }
    size_t o = ((size_t)j0 * 64 + lane) * 8;
    *(us4*)(H + o) = h0; *(us4*)(H + o + 4) = h1;
    *(us4*)(L + o) = l0; *(us4*)(L + o + 4) = l1;
  } else {
    int t = (job - 5) * 1024 + threadIdx.x;
    if (t < NMASKW) {
      uint32_t base = (uint32_t)t * 32u;
      uint32_t w1 = 0, w2 = 0;
#pragma unroll 4
      for (int j = 0; j < 32; ++j) {
        w1 |= (tf_bits32(k10, k11, base + j) >> 31) << j;
        w2 |= (tf_bits32(k20, k21, base + j) >> 31) << j;
      }
      m1[t] = w1;
      m2[t] = w2;
    }
  }
}

// Column-sum the per-chunk hists -> node degree (dinv) + per-node chunk
// prefix cp[c][n] (u16) + per-1024 partial prefix rpp + block sums.
__global__ __launch_bounds__(256) void k_scan1(const unsigned short* __restrict__ hc,
                                               unsigned short* __restrict__ cp,
                                               uint32_t* __restrict__ rpp,
                                               uint32_t* __restrict__ bsum,
                                               float* __restrict__ dinv) {
  __shared__ uint32_t sh[256];
  int t = threadIdx.x;
  int n0 = blockIdx.x * 1024 + t * 4;
  uint32_t v0 = 0, v1 = 0, v2 = 0, v3 = 0;
  if (n0 < NN) {
    for (int c = 0; c < NCHUNK; ++c) {
      const uint32_t* src = (const uint32_t*)(hc + (size_t)c * NN + n0);
      uint32_t a = src[0], b = src[1];
      uint32_t* d = (uint32_t*)(cp + (size_t)c * NN + n0);
      d[0] = (v0 & 0xffffu) | (v1 << 16);
      d[1] = (v2 & 0xffffu) | (v3 << 16);
      v0 += a & 0xffffu; v1 += a >> 16;
      v2 += b & 0xffffu; v3 += b >> 16;
    }
    dinv[n0]     = 1.0f / sqrtf((float)(v0 + 1u));
    dinv[n0 + 1] = 1.0f / sqrtf((float)(v1 + 1u));
    dinv[n0 + 2] = 1.0f / sqrtf((float)(v2 + 1u));
    dinv[n0 + 3] = 1.0f / sqrtf((float)(v3 + 1u));
  }
  uint32_t s = v0 + v1 + v2 + v3;
  sh[t] = s;
  __syncthreads();
  for (int off = 1; off < 256; off <<= 1) {
    uint32_t x = sh[t];
    if (t >= off) x += sh[t - off];
    __syncthreads();
    sh[t] = x;
    __syncthreads();
  }
  uint32_t run = (t > 0) ? sh[t - 1] : 0u;
  if (t == 255) bsum[blockIdx.x] = sh[255];
  if (n0 < NN) {
    rpp[n0] = run;       run += v0;
    rpp[n0 + 1] = run;   run += v1;
    rpp[n0 + 2] = run;   run += v2;
    rpp[n0 + 3] = run;
  }
}

// Parallel exclusive scan of the 98 block sums (single block). Also sets
// rpp[NN] so that rp_final[NN] = rpp[NN] + bsumP[NN>>10] == NE.
__global__ __launch_bounds__(128) void k_scan2(const uint32_t* __restrict__ bsum,
                                               uint32_t* __restrict__ bsumP,
                                               uint32_t* __restrict__ rpp, int nb) {
  __shared__ uint32_t sh[128];
  int t = threadIdx.x;
  uint32_t v = (t < nb) ? bsum[t] : 0u;
  sh[t] = v;
  __syncthreads();
  for (int off = 1; off < 128; off <<= 1) {
    uint32_t x = sh[t];
    if (t >= off) x += sh[t - off];
    __syncthreads();
    sh[t] = x;
    __syncthreads();
  }
  uint32_t excl = (t > 0) ? sh[t - 1] : 0u;
  if (t < nb) bsumP[t] = excl;
  if (t == nb - 1) rpp[NN] = (uint32_t)NE - excl;  // so final rp[NN] == NE
}

// Scatter without device atomics: within-chunk rank via zeroed LDS packed
// counter; pos = rp[d] + chunkpref[c][d] + rank. 1024 thr = 16 waves/block.
__global__ __launch_bounds__(1024) void k_scat_lds(
    const int* __restrict__ ei, const uint32_t* __restrict__ rpp,
    const uint32_t* __restrict__ bsumP, const unsigned short* __restrict__ cp,
    const float* __restrict__ dinv, uint2* __restrict__ e2) {
  __shared__ uint32_t rk[RSZ / 2];  // 50 KB
  const int r = blockIdx.x & (NRANGE - 1);
  const int c = blockIdx.x >> 2;
  const int lo = r * RSZ;
  for (int i = threadIdx.x; i < RSZ / 2; i += 1024) rk[i] = 0u;
  __syncthreads();
  const int* sp = ei + c * ECHUNK;
  const int* dp = ei + NE + c * ECHUNK;
  const unsigned short* cpc = cp + (size_t)c * NN;
  for (int i = threadIdx.x * 4; i < ECHUNK; i += 4096) {
    int4 s4 = *(const int4*)(sp + i);
    int4 d4 = *(const int4*)(dp + i);
#define SCAT(ss, dd)                                                      \
    {                                                                     \
      uint32_t x = (uint32_t)((dd) - lo);                                 \
      if (x < (uint32_t)RSZ) {                                            \
        uint32_t old = atomicAdd(&rk[x >> 1], (x & 1u) ? 0x10000u : 1u);  \
        uint32_t rank = (x & 1u) ? (old >> 16) : (old & 0xffffu);         \
        uint32_t pos = rpp[dd] + bsumP[(uint32_t)(dd) >> 10] +            \
                       (uint32_t)cpc[dd] + rank;                          \
        uint2 rec;                                                        \
        rec.x = (uint32_t)(ss);                                           \
        rec.y = __float_as_uint(dinv[ss] * dinv[dd]);                     \
        e2[pos] = rec;                                                    \
      }                                                                   \
    }
    SCAT(s4.x, d4.x); SCAT(s4.y, d4.y); SCAT(s4.z, d4.z); SCAT(s4.w, d4.w);
#undef SCAT
  }
}

// Layer-1 GEMM: A is f32 (x), split hi/lo in-register. 32 rows/wave (two
// 16-row groups share every B-fragment load -> half the W re-fetch).
__global__ __launch_bounds__(256) void k_gemm1(
    const float* __restrict__ A, const unsigned short* __restrict__ Wh,
    const unsigned short* __restrict__ Wl, unsigned short* __restrict__ C) {
  constexpr int NT = 8;  // DOUT=128
  const int w = threadIdx.x >> 6;
  const int lane = threadIdx.x & 63;
  const int row0 = blockIdx.x * 128 + w * 32;
  const int aoff = (lane >> 4) * 8;
  s16x8 afh[2][4], afl[2][4];
#pragma unroll
  for (int g = 0; g < 2; ++g) {
    int ar = row0 + g * 16 + (lane & 15);
    if (ar >= NN) ar = NN - 1;
#pragma unroll
    for (int kk = 0; kk < 4; ++kk) {
      f4 v0 = *(const f4*)(A + (size_t)ar * 128 + kk * 32 + aoff);
      f4 v1 = *(const f4*)(A + (size_t)ar * 128 + kk * 32 + aoff + 4);
#pragma unroll
      for (int j = 0; j < 4; ++j) {
        unsigned short h = f2bf(v0[j]);
        afh[g][kk][j] = (short)h;
        afl[g][kk][j] = (short)f2bf(v0[j] - bf2f(h));
        unsigned short h2 = f2bf(v1[j]);
        afh[g][kk][j + 4] = (short)h2;
        afl[g][kk][j + 4] = (short)f2bf(v1[j] - bf2f(h2));
      }
    }
  }
  f4 acc[2][NT];
#pragma unroll
  for (int g = 0; g < 2; ++g)
#pragma unroll
    for (int t = 0; t < NT; ++t) acc[g][t] = (f4){0.f, 0.f, 0.f, 0.f};
#pragma unroll
  for (int ct = 0; ct < NT; ++ct) {
#pragma unroll
    for (int kk = 0; kk < 4; ++kk) {
      size_t bo = ((size_t)(ct * 4 + kk) * 64 + lane) * 8;
      s16x8 bh = *(const s16x8*)(Wh + bo);
      s16x8 bl = *(const s16x8*)(Wl + bo);
#pragma unroll
      for (int g = 0; g < 2; ++g) {
        acc[g][ct] = __builtin_amdgcn_mfma_f32_16x16x32_bf16(afh[g][kk], bh, acc[g][ct], 0, 0, 0);
        acc[g][ct] = __builtin_amdgcn_mfma_f32_16x16x32_bf16(afh[g][kk], bl, acc[g][ct], 0, 0, 0);
        acc[g][ct] = __builtin_amdgcn_mfma_f32_16x16x32_bf16(afl[g][kk], bh, acc[g][ct], 0, 0, 0);
      }
    }
  }
  const int cbase = lane & 15;
#pragma unroll
  for (int g = 0; g < 2; ++g) {
    const int rbase = row0 + g * 16 + (lane >> 4) * 4;
#pragma unroll
    for (int ct = 0; ct < NT; ++ct) {
#pragma unroll
      for (int r = 0; r < 4; ++r) {
        int gr = rbase + r;
        if (gr < NN) C[(size_t)gr * 128 + ct * 16 + cbase] = f2bf(acc[g][ct][r]);
      }
    }
  }
}

// Layers 2/3 GEMM: A from hi/lo bf16 arrays. 32 rows/wave.
template <int DOUT>
__global__ __launch_bounds__(256) void k_gemm_mfma(
    const unsigned short* __restrict__ Ah, const unsigned short* __restrict__ Al,
    const unsigned short* __restrict__ Wh, const unsigned short* __restrict__ Wl,
    unsigned short* __restrict__ C) {
  constexpr int NT = DOUT / 16;
  const int w = threadIdx.x >> 6;
  const int lane = threadIdx.x & 63;
  const int row0 = blockIdx.x * 128 + w * 32;
  const int aoff = (lane >> 4) * 8;
  s16x8 afh[2][4], afl[2][4];
#pragma unroll
  for (int g = 0; g < 2; ++g) {
    int ar = row0 + g * 16 + (lane & 15);
    if (ar >= NN) ar = NN - 1;
#pragma unroll
    for (int kk = 0; kk < 4; ++kk) {
      afh[g][kk] = *(const s16x8*)(Ah + (size_t)ar * 128 + kk * 32 + aoff);
      afl[g][kk] = *(const s16x8*)(Al + (size_t)ar * 128 + kk * 32 + aoff);
    }
  }
  f4 acc[2][NT];
#pragma unroll
  for (int g = 0; g < 2; ++g)
#pragma unroll
    for (int t = 0; t < NT; ++t) acc[g][t] = (f4){0.f, 0.f, 0.f, 0.f};
#pragma unroll
  for (int ct = 0; ct < NT; ++ct) {
#pragma unroll
    for (int kk = 0; kk < 4; ++kk) {
      size_t bo = ((size_t)(ct * 4 + kk) * 64 + lane) * 8;
      s16x8 bh = *(const s16x8*)(Wh + bo);
      s16x8 bl = *(const s16x8*)(Wl + bo);
#pragma unroll
      for (int g = 0; g < 2; ++g) {
        acc[g][ct] = __builtin_amdgcn_mfma_f32_16x16x32_bf16(afh[g][kk], bh, acc[g][ct], 0, 0, 0);
        acc[g][ct] = __builtin_amdgcn_mfma_f32_16x16x32_bf16(afh[g][kk], bl, acc[g][ct], 0, 0, 0);
        acc[g][ct] = __builtin_amdgcn_mfma_f32_16x16x32_bf16(afl[g][kk], bh, acc[g][ct], 0, 0, 0);
      }
    }
  }
  const int cbase = lane & 15;
#pragma unroll
  for (int g = 0; g < 2; ++g) {
    const int rbase = row0 + g * 16 + (lane >> 4) * 4;
#pragma unroll
    for (int ct = 0; ct < NT; ++ct) {
#pragma unroll
      for (int r = 0; r < 4; ++r) {
        int gr = rbase + r;
        if (gr < NN) C[(size_t)gr * DOUT + ct * 16 + cbase] = f2bf(acc[g][ct][r]);
      }
    }
  }
}

// Middle aggregation (D=128): 16-edge chunks (4 row-gathers in flight per
// quarter), edge records (src,w), packed-f32 FMA, shfl cross-quarter reduce.
__global__ __launch_bounds__(256) void k_agg_mid(
    const unsigned short* __restrict__ hb, const uint32_t* __restrict__ rpp,
    const uint32_t* __restrict__ bsumP,
    const uint2* __restrict__ e2, const float* __restrict__ dinv,
    const float* __restrict__ bias, const uint32_t* __restrict__ mask,
    unsigned short* __restrict__ oh, unsigned short* __restrict__ ol) {
  int wid = __builtin_amdgcn_readfirstlane(blockIdx.x * 4 + (threadIdx.x >> 6));
  if (wid >= NN) return;
  const int lane = threadIdx.x & 63;
  const int q = lane >> 4;    // edge slot in group of 4
  const int fl = lane & 15;   // feature block: 8 features at fl*8
  const uint32_t beg = rpp[wid] + bsumP[(uint32_t)wid >> 10];
  const uint32_t end = rpp[wid + 1] + bsumP[(uint32_t)(wid + 1) >> 10];
  const float dv = dinv[wid];
  const float sn = dv * dv;
  const char* hbase = (const char*)hb;
  f2 acc[4];
#pragma unroll
  for (int j = 0; j < 4; ++j) acc[j] = (f2){0.f, 0.f};

#define ACC4(g, wv)                                                        \
  {                                                                        \
    f2 wv2 = {wv, wv};                                                     \
    f2 h0 = {lo16(g.x), hi16(g.x)}; acc[0] += wv2 * h0;                    \
    f2 h1 = {lo16(g.y), hi16(g.y)}; acc[1] += wv2 * h1;                    \
    f2 h2 = {lo16(g.z), hi16(g.z)}; acc[2] += wv2 * h2;                    \
    f2 h3 = {lo16(g.w), hi16(g.w)}; acc[3] += wv2 * h3;                    \
  }

  uint32_t u = beg;
  for (; u + 16 <= end; u += 16) {
    uint2 r0 = e2[u + q];
    uint2 r1 = e2[u + 4 + q];
    uint2 r2 = e2[u + 8 + q];
    uint2 r3 = e2[u + 12 + q];
    uint4 g0 = *(const uint4*)(hbase + ((size_t)r0.x << 8) + fl * 16);
    uint4 g1 = *(const uint4*)(hbase + ((size_t)r1.x << 8) + fl * 16);
    uint4 g2 = *(const uint4*)(hbase + ((size_t)r2.x << 8) + fl * 16);
    uint4 g3 = *(const uint4*)(hbase + ((size_t)r3.x << 8) + fl * 16);
    float w0 = __uint_as_float(r0.y), w1 = __uint_as_float(r1.y);
    float w2 = __uint_as_float(r2.y), w3 = __uint_as_float(r3.y);
    ACC4(g0, w0); ACC4(g1, w1); ACC4(g2, w2); ACC4(g3, w3);
  }
  for (; u < end; u += 4) {  // tail: 4 slots, weight-zeroed OOB
    uint32_t idx = u + (uint32_t)q;
    uint32_t cidx = idx < end ? idx : end - 1u;
    uint2 r = e2[cidx];
    float w = (idx < end) ? __uint_as_float(r.y) : 0.f;
    uint4 g = *(const uint4*)(hbase + ((size_t)r.x << 8) + fl * 16);
    ACC4(g, w);
  }
#undef ACC4

#pragma unroll
  for (int j = 0; j < 4; ++j) {
    acc[j][0] += __shfl_xor(acc[j][0], 16);
    acc[j][1] += __shfl_xor(acc[j][1], 16);
    acc[j][0] += __shfl_xor(acc[j][0], 32);
    acc[j][1] += __shfl_xor(acc[j][1], 32);
  }

  // self-loop + bias + relu + dropout
  uint4 qs = *(const uint4*)(hbase + ((size_t)(uint32_t)wid << 8) + fl * 16);
  f2 snv = {sn, sn};
  f2 h0 = {lo16(qs.x), hi16(qs.x)};
  f2 h1 = {lo16(qs.y), hi16(qs.y)};
  f2 h2 = {lo16(qs.z), hi16(qs.z)};
  f2 h3 = {lo16(qs.w), hi16(qs.w)};
  acc[0] += snv * h0; acc[1] += snv * h1;
  acc[2] += snv * h2; acc[3] += snv * h3;
#pragma unroll
  for (int j = 0; j < 4; ++j) acc[j] += *(const f2*)(bias + fl * 8 + 2 * j);

  uint32_t mw = mask[(uint32_t)wid * 4u + (uint32_t)(fl >> 2)];
  uint32_t bb = (uint32_t)((fl & 3) * 8);
  uint32_t hw[4], lw[4];
#pragma unroll
  for (int j = 0; j < 4; ++j) {
    float a0 = fmaxf(acc[j][0], 0.f);
    float a1 = fmaxf(acc[j][1], 0.f);
    a0 = ((mw >> (bb + 2 * j)) & 1u) ? 0.f : a0 * 2.f;
    a1 = ((mw >> (bb + 2 * j + 1)) & 1u) ? 0.f : a1 * 2.f;
    unsigned short hh0 = f2bf(a0), hh1 = f2bf(a1);
    unsigned short g0 = f2bf(a0 - bf2f(hh0)), g1 = f2bf(a1 - bf2f(hh1));
    hw[j] = (uint32_t)hh0 | ((uint32_t)hh1 << 16);
    lw[j] = (uint32_t)g0 | ((uint32_t)g1 << 16);
  }
  if (q == 0) {
    uint4 v = {hw[0], hw[1], hw[2], hw[3]};
    *(uint4*)(oh + (size_t)(uint32_t)wid * 128 + fl * 8) = v;
  } else if (q == 1) {
    uint4 v = {lw[0], lw[1], lw[2], lw[3]};
    *(uint4*)(ol + (size_t)(uint32_t)wid * 128 + fl * 8) = v;
  }
}

// Final aggregation (D=64): 8B/lane gathers, 16-edge chunks, packed FMA.
__global__ __launch_bounds__(256) void k_agg_final(
    const unsigned short* __restrict__ hb, const uint32_t* __restrict__ rpp,
    const uint32_t* __restrict__ bsumP,
    const uint2* __restrict__ e2, const float* __restrict__ dinv,
    const float* __restrict__ bias, float* __restrict__ out) {
  int wid = __builtin_amdgcn_readfirstlane(blockIdx.x * 4 + (threadIdx.x >> 6));
  if (wid >= NN) return;
  const int lane = threadIdx.x & 63;
  const int q = lane >> 4;
  const int fl = lane & 15;  // 4 features at fl*4
  const uint32_t beg = rpp[wid] + bsumP[(uint32_t)wid >> 10];
  const uint32_t end = rpp[wid + 1] + bsumP[(uint32_t)(wid + 1) >> 10];
  const float dv = dinv[wid];
  const float sn = dv * dv;
  const char* hbase = (const char*)hb;
  f2 acc[2];
  acc[0] = (f2){0.f, 0.f};
  acc[1] = (f2){0.f, 0.f};

#define ACC2(g, wv)                                                        \
  {                                                                        \
    f2 wv2 = {wv, wv};                                                     \
    f2 h0 = {lo16(g.x), hi16(g.x)}; acc[0] += wv2 * h0;                    \
    f2 h1 = {lo16(g.y), hi16(g.y)}; acc[1] += wv2 * h1;                    \
  }

  uint32_t u = beg;
  for (; u + 16 <= end; u += 16) {
    uint2 r0 = e2[u + q];
    uint2 r1 = e2[u + 4 + q];
    uint2 r2 = e2[u + 8 + q];
    uint2 r3 = e2[u + 12 + q];
    uint2 g0 = *(const uint2*)(hbase + ((size_t)r0.x << 7) + fl * 8);
    uint2 g1 = *(const uint2*)(hbase + ((size_t)r1.x << 7) + fl * 8);
    uint2 g2 = *(const uint2*)(hbase + ((size_t)r2.x << 7) + fl * 8);
    uint2 g3 = *(const uint2*)(hbase + ((size_t)r3.x << 7) + fl * 8);
    float w0 = __uint_as_float(r0.y), w1 = __uint_as_float(r1.y);
    float w2 = __uint_as_float(r2.y), w3 = __uint_as_float(r3.y);
    ACC2(g0, w0); ACC2(g1, w1); ACC2(g2, w2); ACC2(g3, w3);
  }
  for (; u < end; u += 4) {
    uint32_t idx = u + (uint32_t)q;
    uint32_t cidx = idx < end ? idx : end - 1u;
    uint2 r = e2[cidx];
    float w = (idx < end) ? __uint_as_float(r.y) : 0.f;
    uint2 g = *(const uint2*)(hbase + ((size_t)r.x << 7) + fl * 8);
    ACC2(g, w);
  }
#undef ACC2

#pragma unroll
  for (int j = 0; j < 2; ++j) {
    acc[j][0] += __shfl_xor(acc[j][0], 16);
    acc[j][1] += __shfl_xor(acc[j][1], 16);
    acc[j][0] += __shfl_xor(acc[j][0], 32);
    acc[j][1] += __shfl_xor(acc[j][1], 32);
  }

  uint2 qs = *(const uint2*)(hbase + ((size_t)(uint32_t)wid << 7) + fl * 8);
  f2 snv = {sn, sn};
  f2 h0 = {lo16(qs.x), hi16(qs.x)};
  f2 h1 = {lo16(qs.y), hi16(qs.y)};
  acc[0] += snv * h0;
  acc[1] += snv * h1;
  acc[0] += *(const f2*)(bias + fl * 4);
  acc[1] += *(const f2*)(bias + fl * 4 + 2);
  if (q == 0) {
    f4 v = {acc[0][0], acc[0][1], acc[1][0], acc[1][1]};
    *(f4*)(out + (size_t)(uint32_t)wid * 64 + fl * 4) = v;
  }
}

extern "C" void kernel_launch(void* const* d_in, const int* in_sizes, int n_in,
                              void* d_out, int out_size, void* d_ws, size_t ws_size,
                              hipStream_t stream) {
  (void)in_sizes; (void)n_in; (void)out_size; (void)ws_size;
  const float* x  = (const float*)d_in[0];
  const float* W1 = (const float*)d_in[1];
  const float* b1 = (const float*)d_in[2];
  const float* W2 = (const float*)d_in[3];
  const float* b2 = (const float*)d_in[4];
  const float* W3 = (const float*)d_in[5];
  const float* b3 = (const float*)d_in[6];
  const int* ei   = (const int*)d_in[7];
  float* out = (float*)d_out;

  char* p = (char*)d_ws;
  auto alloc = [&](size_t bytes) -> void* {
    void* r = (void*)p;
    p += (bytes + 255) & ~(size_t)255;
    return r;
  };
  float*    dinv  = (float*)alloc((size_t)NN * 4);
  uint32_t* rpp   = (uint32_t*)alloc((size_t)(NN + 1) * 4);
  uint32_t* bsum  = (uint32_t*)alloc(1024);
  uint32_t* bsumP = (uint32_t*)alloc(1024);
  uint2*    e2    = (uint2*)alloc((size_t)NE * 8);
  uint32_t* m1    = (uint32_t*)alloc((size_t)NMASKW * 4);
  uint32_t* m2    = (uint32_t*)alloc((size_t)NMASKW * 4);
  unsigned short* ah = (unsigned short*)alloc((size_t)NN * 128 * 2);
  unsigned short* al = (unsigned short*)alloc((size_t)NN * 128 * 2);
  unsigned short* hb = (unsigned short*)alloc((size_t)NN * 128 * 2);
  unsigned short* w1h = (unsigned short*)alloc(32 * 64 * 8 * 2);
  unsigned short* w1l = (unsigned short*)alloc(32 * 64 * 8 * 2);
  unsigned short* w2h = (unsigned short*)alloc(32 * 64 * 8 * 2);
  unsigned short* w2l = (unsigned short*)alloc(32 * 64 * 8 * 2);
  unsigned short* w3h = (unsigned short*)alloc(16 * 64 * 8 * 2);
  unsigned short* w3l = (unsigned short*)alloc(16 * 64 * 8 * 2);

  // hc (per-chunk hist) and cp (chunk prefix) alias ah/al: both are dead
  // before agg_mid first writes ah/al.
  unsigned short* hc = ah;  // [NCHUNK][NN] u16 = 12.8 MB <= 25.6 MB
  unsigned short* cp = al;  // [NCHUNK][NN] u16

  // JAX: kd1, kd2 = split(key(42)) — partitionable/fold-like split.
  uint32_t kd1a, kd1b, kd2a, kd2b;
  threefry2x32(0u, 42u, 0u, 0u, &kd1a, &kd1b);
  threefry2x32(0u, 42u, 0u, 1u, &kd2a, &kd2b);

  const int gbScan = (NN + 1023) / 1024;  // 98
  const int gbGemm = (NN + 127) / 128;    // 782 (32 rows/wave)
  const int gbAgg = (NN + 3) / 4;

  // k_pre grid: 512 interleaved (256 hist even / 256 maskw odd) + 140 maskw.
  k_pre<<<652, 1024, 0, stream>>>(ei, hc, m1, m2, kd1a, kd1b, kd2a, kd2b,
                                  W1, W2, W3, w1h, w1l, w2h, w2l, w3h, w3l);
  k_scan1<<<gbScan, 256, 0, stream>>>(hc, cp, rpp, bsum, dinv);
  k_scan2<<<1, 128, 0, stream>>>(bsum, bsumP, rpp, gbScan);
  k_scat_lds<<<NRANGE * NCHUNK, 1024, 0, stream>>>(ei, rpp, bsumP, cp, dinv, e2);

  k_gemm1<<<gbGemm, 256, 0, stream>>>(x, w1h, w1l, hb);
  k_agg_mid<<<gbAgg, 256, 0, stream>>>(hb, rpp, bsumP, e2, dinv, b1, m1, ah, al);
  k_gemm_mfma<128><<<gbGemm, 256, 0, stream>>>(ah, al, w2h, w2l, hb);
  k_agg_mid<<<gbAgg, 256, 0, stream>>>(hb, rpp, bsumP, e2, dinv, b2, m2, ah, al);
  k_gemm_mfma<64><<<gbGemm, 256, 0, stream>>>(ah, al, w3h, w3l, hb);
  k_agg_final<<<gbAgg, 256, 0, stream>>>(hb, rpp, bsumP, e2, dinv, b3, out);
}

// Round 17
// 388.057 us; speedup vs baseline: 1.0710x; 1.0710x over previous
//
#include <hip/hip_runtime.h>
#include <stdint.h>

#define NN 100000
#define NE 1600000
#define NMASKW 400000   // (NN*128)/32 mask words per layer
#define NRANGE 4
#define RSZ 25000       // NN / NRANGE
#define NCHUNK 64
#define ECHUNK 25000    // NE / NCHUNK
#define MASK_BLKS 1563
#define WSPL_BLKS 20

typedef float f4 __attribute__((ext_vector_type(4)));
typedef float f2 __attribute__((ext_vector_type(2)));
typedef unsigned short us4 __attribute__((ext_vector_type(4)));
typedef short s16x8 __attribute__((ext_vector_type(8)));

__device__ inline float bf2f(unsigned short u) {
  return __uint_as_float(((uint32_t)u) << 16);
}
__device__ inline unsigned short f2bf(float f) {  // round-to-nearest-even
  uint32_t u = __float_as_uint(f);
  return (unsigned short)((u + 0x7fffu + ((u >> 16) & 1u)) >> 16);
}
__device__ inline float lo16(uint32_t q) { return __uint_as_float(q << 16); }
__device__ inline float hi16(uint32_t q) { return __uint_as_float(q & 0xffff0000u); }

// Threefry-2x32, 20 rounds (Random123 / JAX exact).
__host__ __device__ inline void threefry2x32(uint32_t k0, uint32_t k1,
                                             uint32_t x0, uint32_t x1,
                                             uint32_t* y0, uint32_t* y1) {
  uint32_t ks[3] = {k0, k1, k0 ^ k1 ^ 0x1BD11BDAu};
  x0 += ks[0]; x1 += ks[1];
  const uint32_t R[2][4] = {{13u, 15u, 26u, 6u}, {17u, 29u, 16u, 24u}};
#pragma unroll
  for (int i = 0; i < 5; ++i) {
#pragma unroll
    for (int j = 0; j < 4; ++j) {
      uint32_t r = R[i & 1][j];
      x0 += x1;
      x1 = (x1 << r) | (x1 >> (32u - r));
      x1 ^= x0;
    }
    x0 += ks[(i + 1) % 3];
    x1 += ks[(i + 2) % 3] + (uint32_t)(i + 1);
  }
  *y0 = x0; *y1 = x1;
}

__device__ inline uint32_t tf_bits32(uint32_t k0, uint32_t k1, uint32_t idx) {
  uint32_t a, b;
  threefry2x32(k0, k1, 0u, idx, &a, &b);
  return a ^ b;
}

// LDS-private histogram: block (range r, chunk c) counts dsts of its edge
// chunk within its node range. Packed u16 pairs (deg << 65535: no carry).
// No device-scope atomics. 1024 threads = 16 waves/block for latency cover.
__global__ __launch_bounds__(1024) void k_hist_lds(const int* __restrict__ ei,
                                                   unsigned short* __restrict__ hc) {
  __shared__ uint32_t h[RSZ / 2];  // 50 KB
  const int r = blockIdx.x & (NRANGE - 1);
  const int c = blockIdx.x >> 2;
  const int lo = r * RSZ;
  for (int i = threadIdx.x; i < RSZ / 2; i += 1024) h[i] = 0u;
  __syncthreads();
  const int* dp = ei + NE + c * ECHUNK;
  for (int i = threadIdx.x * 4; i < ECHUNK; i += 4096) {
    int4 d4 = *(const int4*)(dp + i);
#define CNT(dd)                                                           \
    {                                                                     \
      uint32_t x = (uint32_t)((dd) - lo);                                 \
      if (x < (uint32_t)RSZ)                                              \
        atomicAdd(&h[x >> 1], (x & 1u) ? 0x10000u : 1u);                  \
    }
    CNT(d4.x); CNT(d4.y); CNT(d4.z); CNT(d4.w);
#undef CNT
  }
  __syncthreads();
  uint32_t* dst = (uint32_t*)(hc + (size_t)c * NN + lo);
  for (int i = threadIdx.x; i < RSZ / 2; i += 1024) dst[i] = h[i];
}

// Column-sum the per-chunk hists -> node degree (dinv) + per-node chunk
// prefix cp[c][n] (u16) + per-1024 partial prefix rpp + block sums.
__global__ __launch_bounds__(256) void k_scan1(const unsigned short* __restrict__ hc,
                                               unsigned short* __restrict__ cp,
                                               uint32_t* __restrict__ rpp,
                                               uint32_t* __restrict__ bsum,
                                               float* __restrict__ dinv) {
  __shared__ uint32_t sh[256];
  int t = threadIdx.x;
  int n0 = blockIdx.x * 1024 + t * 4;
  uint32_t v0 = 0, v1 = 0, v2 = 0, v3 = 0;
  if (n0 < NN) {
    for (int c = 0; c < NCHUNK; ++c) {
      const uint32_t* src = (const uint32_t*)(hc + (size_t)c * NN + n0);
      uint32_t a = src[0], b = src[1];
      uint32_t* d = (uint32_t*)(cp + (size_t)c * NN + n0);
      d[0] = (v0 & 0xffffu) | (v1 << 16);
      d[1] = (v2 & 0xffffu) | (v3 << 16);
      v0 += a & 0xffffu; v1 += a >> 16;
      v2 += b & 0xffffu; v3 += b >> 16;
    }
    dinv[n0]     = 1.0f / sqrtf((float)(v0 + 1u));
    dinv[n0 + 1] = 1.0f / sqrtf((float)(v1 + 1u));
    dinv[n0 + 2] = 1.0f / sqrtf((float)(v2 + 1u));
    dinv[n0 + 3] = 1.0f / sqrtf((float)(v3 + 1u));
  }
  uint32_t s = v0 + v1 + v2 + v3;
  sh[t] = s;
  __syncthreads();
  for (int off = 1; off < 256; off <<= 1) {
    uint32_t x = sh[t];
    if (t >= off) x += sh[t - off];
    __syncthreads();
    sh[t] = x;
    __syncthreads();
  }
  uint32_t run = (t > 0) ? sh[t - 1] : 0u;
  if (t == 255) bsum[blockIdx.x] = sh[255];
  if (n0 < NN) {
    rpp[n0] = run;       run += v0;
    rpp[n0 + 1] = run;   run += v1;
    rpp[n0 + 2] = run;   run += v2;
    rpp[n0 + 3] = run;
  }
}

// Parallel exclusive scan of the 98 block sums (single block). Also sets
// rpp[NN] so that rp_final[NN] = rpp[NN] + bsumP[NN>>10] == NE.
__global__ __launch_bounds__(128) void k_scan2(const uint32_t* __restrict__ bsum,
                                               uint32_t* __restrict__ bsumP,
                                               uint32_t* __restrict__ rpp, int nb) {
  __shared__ uint32_t sh[128];
  int t = threadIdx.x;
  uint32_t v = (t < nb) ? bsum[t] : 0u;
  sh[t] = v;
  __syncthreads();
  for (int off = 1; off < 128; off <<= 1) {
    uint32_t x = sh[t];
    if (t >= off) x += sh[t - off];
    __syncthreads();
    sh[t] = x;
    __syncthreads();
  }
  uint32_t excl = (t > 0) ? sh[t - 1] : 0u;
  if (t < nb) bsumP[t] = excl;
  if (t == nb - 1) rpp[NN] = (uint32_t)NE - excl;  // so final rp[NN] == NE
}

// Fused: wsplit (blocks 0..19) + dropout masks (rest). Pure VALU/streaming.
__global__ __launch_bounds__(256) void k_maskwsplit(
    uint32_t* __restrict__ m1, uint32_t* __restrict__ m2,
    uint32_t k10, uint32_t k11, uint32_t k20, uint32_t k21,
    const float* __restrict__ W1, const float* __restrict__ W2,
    const float* __restrict__ W3,
    unsigned short* __restrict__ w1h, unsigned short* __restrict__ w1l,
    unsigned short* __restrict__ w2h, unsigned short* __restrict__ w2l,
    unsigned short* __restrict__ w3h, unsigned short* __restrict__ w3l) {
  int b = blockIdx.x;
  if (b < WSPL_BLKS) {
    int bb = b * 4 + (threadIdx.x >> 6);  // 0..79
    int lane = threadIdx.x & 63;
    const float* W; unsigned short *H, *L; int dout, j0;
    if (bb < 32)      { W = W1; H = w1h; L = w1l; dout = 128; j0 = bb; }
    else if (bb < 64) { W = W2; H = w2h; L = w2l; dout = 128; j0 = bb - 32; }
    else              { W = W3; H = w3h; L = w3l; dout = 64;  j0 = bb - 64; }
    int kk = j0 & 3;
    int ct = j0 >> 2;
    int kbase = kk * 32 + (lane >> 4) * 8;
    int col = ct * 16 + (lane & 15);
    us4 h0, h1, l0, l1;
#pragma unroll
    for (int j = 0; j < 4; ++j) {
      float v = W[(size_t)(kbase + j) * dout + col];
      h0[j] = f2bf(v);
      l0[j] = f2bf(v - bf2f(h0[j]));
      float v2 = W[(size_t)(kbase + 4 + j) * dout + col];
      h1[j] = f2bf(v2);
      l1[j] = f2bf(v2 - bf2f(h1[j]));
    }
    size_t o = ((size_t)j0 * 64 + lane) * 8;
    *(us4*)(H + o) = h0; *(us4*)(H + o + 4) = h1;
    *(us4*)(L + o) = l0; *(us4*)(L + o + 4) = l1;
  } else {
    int t = (b - WSPL_BLKS) * 256 + threadIdx.x;
    if (t < NMASKW) {
      uint32_t base = (uint32_t)t * 32u;
      uint32_t w1 = 0, w2 = 0;
#pragma unroll 4
      for (int j = 0; j < 32; ++j) {
        w1 |= (tf_bits32(k10, k11, base + j) >> 31) << j;
        w2 |= (tf_bits32(k20, k21, base + j) >> 31) << j;
      }
      m1[t] = w1;
      m2[t] = w2;
    }
  }
}

// Scatter without device atomics: within-chunk rank via zeroed LDS packed
// counter; pos = rp[d] + chunkpref[c][d] + rank. 1024 thr = 16 waves/block.
__global__ __launch_bounds__(1024) void k_scat_lds(
    const int* __restrict__ ei, const uint32_t* __restrict__ rpp,
    const uint32_t* __restrict__ bsumP, const unsigned short* __restrict__ cp,
    const float* __restrict__ dinv, uint2* __restrict__ e2) {
  __shared__ uint32_t rk[RSZ / 2];  // 50 KB
  const int r = blockIdx.x & (NRANGE - 1);
  const int c = blockIdx.x >> 2;
  const int lo = r * RSZ;
  for (int i = threadIdx.x; i < RSZ / 2; i += 1024) rk[i] = 0u;
  __syncthreads();
  const int* sp = ei + c * ECHUNK;
  const int* dp = ei + NE + c * ECHUNK;
  const unsigned short* cpc = cp + (size_t)c * NN;
  for (int i = threadIdx.x * 4; i < ECHUNK; i += 4096) {
    int4 s4 = *(const int4*)(sp + i);
    int4 d4 = *(const int4*)(dp + i);
#define SCAT(ss, dd)                                                      \
    {                                                                     \
      uint32_t x = (uint32_t)((dd) - lo);                                 \
      if (x < (uint32_t)RSZ) {                                            \
        uint32_t old = atomicAdd(&rk[x >> 1], (x & 1u) ? 0x10000u : 1u);  \
        uint32_t rank = (x & 1u) ? (old >> 16) : (old & 0xffffu);         \
        uint32_t pos = rpp[dd] + bsumP[(uint32_t)(dd) >> 10] +            \
                       (uint32_t)cpc[dd] + rank;                          \
        uint2 rec;                                                        \
        rec.x = (uint32_t)(ss);                                           \
        rec.y = __float_as_uint(dinv[ss] * dinv[dd]);                     \
        e2[pos] = rec;                                                    \
      }                                                                   \
    }
    SCAT(s4.x, d4.x); SCAT(s4.y, d4.y); SCAT(s4.z, d4.z); SCAT(s4.w, d4.w);
#undef SCAT
  }
}

// Layer-1 GEMM: A is f32 (x), split hi/lo in-register. 32 rows/wave (two
// 16-row groups share every B-fragment load -> half the W re-fetch).
__global__ __launch_bounds__(256) void k_gemm1(
    const float* __restrict__ A, const unsigned short* __restrict__ Wh,
    const unsigned short* __restrict__ Wl, unsigned short* __restrict__ C) {
  constexpr int NT = 8;  // DOUT=128
  const int w = threadIdx.x >> 6;
  const int lane = threadIdx.x & 63;
  const int row0 = blockIdx.x * 128 + w * 32;
  const int aoff = (lane >> 4) * 8;
  s16x8 afh[2][4], afl[2][4];
#pragma unroll
  for (int g = 0; g < 2; ++g) {
    int ar = row0 + g * 16 + (lane & 15);
    if (ar >= NN) ar = NN - 1;
#pragma unroll
    for (int kk = 0; kk < 4; ++kk) {
      f4 v0 = *(const f4*)(A + (size_t)ar * 128 + kk * 32 + aoff);
      f4 v1 = *(const f4*)(A + (size_t)ar * 128 + kk * 32 + aoff + 4);
#pragma unroll
      for (int j = 0; j < 4; ++j) {
        unsigned short h = f2bf(v0[j]);
        afh[g][kk][j] = (short)h;
        afl[g][kk][j] = (short)f2bf(v0[j] - bf2f(h));
        unsigned short h2 = f2bf(v1[j]);
        afh[g][kk][j + 4] = (short)h2;
        afl[g][kk][j + 4] = (short)f2bf(v1[j] - bf2f(h2));
      }
    }
  }
  f4 acc[2][NT];
#pragma unroll
  for (int g = 0; g < 2; ++g)
#pragma unroll
    for (int t = 0; t < NT; ++t) acc[g][t] = (f4){0.f, 0.f, 0.f, 0.f};
#pragma unroll
  for (int ct = 0; ct < NT; ++ct) {
#pragma unroll
    for (int kk = 0; kk < 4; ++kk) {
      size_t bo = ((size_t)(ct * 4 + kk) * 64 + lane) * 8;
      s16x8 bh = *(const s16x8*)(Wh + bo);
      s16x8 bl = *(const s16x8*)(Wl + bo);
#pragma unroll
      for (int g = 0; g < 2; ++g) {
        acc[g][ct] = __builtin_amdgcn_mfma_f32_16x16x32_bf16(afh[g][kk], bh, acc[g][ct], 0, 0, 0);
        acc[g][ct] = __builtin_amdgcn_mfma_f32_16x16x32_bf16(afh[g][kk], bl, acc[g][ct], 0, 0, 0);
        acc[g][ct] = __builtin_amdgcn_mfma_f32_16x16x32_bf16(afl[g][kk], bh, acc[g][ct], 0, 0, 0);
      }
    }
  }
  const int cbase = lane & 15;
#pragma unroll
  for (int g = 0; g < 2; ++g) {
    const int rbase = row0 + g * 16 + (lane >> 4) * 4;
#pragma unroll
    for (int ct = 0; ct < NT; ++ct) {
#pragma unroll
      for (int r = 0; r < 4; ++r) {
        int gr = rbase + r;
        if (gr < NN) C[(size_t)gr * 128 + ct * 16 + cbase] = f2bf(acc[g][ct][r]);
      }
    }
  }
}

// Layers 2/3 GEMM: A from hi/lo bf16 arrays. 32 rows/wave.
template <int DOUT>
__global__ __launch_bounds__(256) void k_gemm_mfma(
    const unsigned short* __restrict__ Ah, const unsigned short* __restrict__ Al,
    const unsigned short* __restrict__ Wh, const unsigned short* __restrict__ Wl,
    unsigned short* __restrict__ C) {
  constexpr int NT = DOUT / 16;
  const int w = threadIdx.x >> 6;
  const int lane = threadIdx.x & 63;
  const int row0 = blockIdx.x * 128 + w * 32;
  const int aoff = (lane >> 4) * 8;
  s16x8 afh[2][4], afl[2][4];
#pragma unroll
  for (int g = 0; g < 2; ++g) {
    int ar = row0 + g * 16 + (lane & 15);
    if (ar >= NN) ar = NN - 1;
#pragma unroll
    for (int kk = 0; kk < 4; ++kk) {
      afh[g][kk] = *(const s16x8*)(Ah + (size_t)ar * 128 + kk * 32 + aoff);
      afl[g][kk] = *(const s16x8*)(Al + (size_t)ar * 128 + kk * 32 + aoff);
    }
  }
  f4 acc[2][NT];
#pragma unroll
  for (int g = 0; g < 2; ++g)
#pragma unroll
    for (int t = 0; t < NT; ++t) acc[g][t] = (f4){0.f, 0.f, 0.f, 0.f};
#pragma unroll
  for (int ct = 0; ct < NT; ++ct) {
#pragma unroll
    for (int kk = 0; kk < 4; ++kk) {
      size_t bo = ((size_t)(ct * 4 + kk) * 64 + lane) * 8;
      s16x8 bh = *(const s16x8*)(Wh + bo);
      s16x8 bl = *(const s16x8*)(Wl + bo);
#pragma unroll
      for (int g = 0; g < 2; ++g) {
        acc[g][ct] = __builtin_amdgcn_mfma_f32_16x16x32_bf16(afh[g][kk], bh, acc[g][ct], 0, 0, 0);
        acc[g][ct] = __builtin_amdgcn_mfma_f32_16x16x32_bf16(afh[g][kk], bl, acc[g][ct], 0, 0, 0);
        acc[g][ct] = __builtin_amdgcn_mfma_f32_16x16x32_bf16(afl[g][kk], bh, acc[g][ct], 0, 0, 0);
      }
    }
  }
  const int cbase = lane & 15;
#pragma unroll
  for (int g = 0; g < 2; ++g) {
    const int rbase = row0 + g * 16 + (lane >> 4) * 4;
#pragma unroll
    for (int ct = 0; ct < NT; ++ct) {
#pragma unroll
      for (int r = 0; r < 4; ++r) {
        int gr = rbase + r;
        if (gr < NN) C[(size_t)gr * DOUT + ct * 16 + cbase] = f2bf(acc[g][ct][r]);
      }
    }
  }
}

// Middle aggregation (D=128): 16-edge chunks (4 row-gathers in flight per
// quarter), edge records (src,w), packed-f32 FMA, shfl cross-quarter reduce.
__global__ __launch_bounds__(256) void k_agg_mid(
    const unsigned short* __restrict__ hb, const uint32_t* __restrict__ rpp,
    const uint32_t* __restrict__ bsumP,
    const uint2* __restrict__ e2, const float* __restrict__ dinv,
    const float* __restrict__ bias, const uint32_t* __restrict__ mask,
    unsigned short* __restrict__ oh, unsigned short* __restrict__ ol) {
  int wid = __builtin_amdgcn_readfirstlane(blockIdx.x * 4 + (threadIdx.x >> 6));
  if (wid >= NN) return;
  const int lane = threadIdx.x & 63;
  const int q = lane >> 4;    // edge slot in group of 4
  const int fl = lane & 15;   // feature block: 8 features at fl*8
  const uint32_t beg = rpp[wid] + bsumP[(uint32_t)wid >> 10];
  const uint32_t end = rpp[wid + 1] + bsumP[(uint32_t)(wid + 1) >> 10];
  const float dv = dinv[wid];
  const float sn = dv * dv;
  const char* hbase = (const char*)hb;
  f2 acc[4];
#pragma unroll
  for (int j = 0; j < 4; ++j) acc[j] = (f2){0.f, 0.f};

#define ACC4(g, wv)                                                        \
  {                                                                        \
    f2 wv2 = {wv, wv};                                                     \
    f2 h0 = {lo16(g.x), hi16(g.x)}; acc[0] += wv2 * h0;                    \
    f2 h1 = {lo16(g.y), hi16(g.y)}; acc[1] += wv2 * h1;                    \
    f2 h2 = {lo16(g.z), hi16(g.z)}; acc[2] += wv2 * h2;                    \
    f2 h3 = {lo16(g.w), hi16(g.w)}; acc[3] += wv2 * h3;                    \
  }

  uint32_t u = beg;
  for (; u + 16 <= end; u += 16) {
    uint2 r0 = e2[u + q];
    uint2 r1 = e2[u + 4 + q];
    uint2 r2 = e2[u + 8 + q];
    uint2 r3 = e2[u + 12 + q];
    uint4 g0 = *(const uint4*)(hbase + ((size_t)r0.x << 8) + fl * 16);
    uint4 g1 = *(const uint4*)(hbase + ((size_t)r1.x << 8) + fl * 16);
    uint4 g2 = *(const uint4*)(hbase + ((size_t)r2.x << 8) + fl * 16);
    uint4 g3 = *(const uint4*)(hbase + ((size_t)r3.x << 8) + fl * 16);
    float w0 = __uint_as_float(r0.y), w1 = __uint_as_float(r1.y);
    float w2 = __uint_as_float(r2.y), w3 = __uint_as_float(r3.y);
    ACC4(g0, w0); ACC4(g1, w1); ACC4(g2, w2); ACC4(g3, w3);
  }
  for (; u < end; u += 4) {  // tail: 4 slots, weight-zeroed OOB
    uint32_t idx = u + (uint32_t)q;
    uint32_t cidx = idx < end ? idx : end - 1u;
    uint2 r = e2[cidx];
    float w = (idx < end) ? __uint_as_float(r.y) : 0.f;
    uint4 g = *(const uint4*)(hbase + ((size_t)r.x << 8) + fl * 16);
    ACC4(g, w);
  }
#undef ACC4

#pragma unroll
  for (int j = 0; j < 4; ++j) {
    acc[j][0] += __shfl_xor(acc[j][0], 16);
    acc[j][1] += __shfl_xor(acc[j][1], 16);
    acc[j][0] += __shfl_xor(acc[j][0], 32);
    acc[j][1] += __shfl_xor(acc[j][1], 32);
  }

  // self-loop + bias + relu + dropout
  uint4 qs = *(const uint4*)(hbase + ((size_t)(uint32_t)wid << 8) + fl * 16);
  f2 snv = {sn, sn};
  f2 h0 = {lo16(qs.x), hi16(qs.x)};
  f2 h1 = {lo16(qs.y), hi16(qs.y)};
  f2 h2 = {lo16(qs.z), hi16(qs.z)};
  f2 h3 = {lo16(qs.w), hi16(qs.w)};
  acc[0] += snv * h0; acc[1] += snv * h1;
  acc[2] += snv * h2; acc[3] += snv * h3;
#pragma unroll
  for (int j = 0; j < 4; ++j) acc[j] += *(const f2*)(bias + fl * 8 + 2 * j);

  uint32_t mw = mask[(uint32_t)wid * 4u + (uint32_t)(fl >> 2)];
  uint32_t bb = (uint32_t)((fl & 3) * 8);
  uint32_t hw[4], lw[4];
#pragma unroll
  for (int j = 0; j < 4; ++j) {
    float a0 = fmaxf(acc[j][0], 0.f);
    float a1 = fmaxf(acc[j][1], 0.f);
    a0 = ((mw >> (bb + 2 * j)) & 1u) ? 0.f : a0 * 2.f;
    a1 = ((mw >> (bb + 2 * j + 1)) & 1u) ? 0.f : a1 * 2.f;
    unsigned short hh0 = f2bf(a0), hh1 = f2bf(a1);
    unsigned short g0 = f2bf(a0 - bf2f(hh0)), g1 = f2bf(a1 - bf2f(hh1));
    hw[j] = (uint32_t)hh0 | ((uint32_t)hh1 << 16);
    lw[j] = (uint32_t)g0 | ((uint32_t)g1 << 16);
  }
  if (q == 0) {
    uint4 v = {hw[0], hw[1], hw[2], hw[3]};
    *(uint4*)(oh + (size_t)(uint32_t)wid * 128 + fl * 8) = v;
  } else if (q == 1) {
    uint4 v = {lw[0], lw[1], lw[2], lw[3]};
    *(uint4*)(ol + (size_t)(uint32_t)wid * 128 + fl * 8) = v;
  }
}

// Final aggregation (D=64): 8B/lane gathers, 16-edge chunks, packed FMA.
__global__ __launch_bounds__(256) void k_agg_final(
    const unsigned short* __restrict__ hb, const uint32_t* __restrict__ rpp,
    const uint32_t* __restrict__ bsumP,
    const uint2* __restrict__ e2, const float* __restrict__ dinv,
    const float* __restrict__ bias, float* __restrict__ out) {
  int wid = __builtin_amdgcn_readfirstlane(blockIdx.x * 4 + (threadIdx.x >> 6));
  if (wid >= NN) return;
  const int lane = threadIdx.x & 63;
  const int q = lane >> 4;
  const int fl = lane & 15;  // 4 features at fl*4
  const uint32_t beg = rpp[wid] + bsumP[(uint32_t)wid >> 10];
  const uint32_t end = rpp[wid + 1] + bsumP[(uint32_t)(wid + 1) >> 10];
  const float dv = dinv[wid];
  const float sn = dv * dv;
  const char* hbase = (const char*)hb;
  f2 acc[2];
  acc[0] = (f2){0.f, 0.f};
  acc[1] = (f2){0.f, 0.f};

#define ACC2(g, wv)                                                        \
  {                                                                        \
    f2 wv2 = {wv, wv};                                                     \
    f2 h0 = {lo16(g.x), hi16(g.x)}; acc[0] += wv2 * h0;                    \
    f2 h1 = {lo16(g.y), hi16(g.y)}; acc[1] += wv2 * h1;                    \
  }

  uint32_t u = beg;
  for (; u + 16 <= end; u += 16) {
    uint2 r0 = e2[u + q];
    uint2 r1 = e2[u + 4 + q];
    uint2 r2 = e2[u + 8 + q];
    uint2 r3 = e2[u + 12 + q];
    uint2 g0 = *(const uint2*)(hbase + ((size_t)r0.x << 7) + fl * 8);
    uint2 g1 = *(const uint2*)(hbase + ((size_t)r1.x << 7) + fl * 8);
    uint2 g2 = *(const uint2*)(hbase + ((size_t)r2.x << 7) + fl * 8);
    uint2 g3 = *(const uint2*)(hbase + ((size_t)r3.x << 7) + fl * 8);
    float w0 = __uint_as_float(r0.y), w1 = __uint_as_float(r1.y);
    float w2 = __uint_as_float(r2.y), w3 = __uint_as_float(r3.y);
    ACC2(g0, w0); ACC2(g1, w1); ACC2(g2, w2); ACC2(g3, w3);
  }
  for (; u < end; u += 4) {
    uint32_t idx = u + (uint32_t)q;
    uint32_t cidx = idx < end ? idx : end - 1u;
    uint2 r = e2[cidx];
    float w = (idx < end) ? __uint_as_float(r.y) : 0.f;
    uint2 g = *(const uint2*)(hbase + ((size_t)r.x << 7) + fl * 8);
    ACC2(g, w);
  }
#undef ACC2

#pragma unroll
  for (int j = 0; j < 2; ++j) {
    acc[j][0] += __shfl_xor(acc[j][0], 16);
    acc[j][1] += __shfl_xor(acc[j][1], 16);
    acc[j][0] += __shfl_xor(acc[j][0], 32);
    acc[j][1] += __shfl_xor(acc[j][1], 32);
  }

  uint2 qs = *(const uint2*)(hbase + ((size_t)(uint32_t)wid << 7) + fl * 8);
  f2 snv = {sn, sn};
  f2 h0 = {lo16(qs.x), hi16(qs.x)};
  f2 h1 = {lo16(qs.y), hi16(qs.y)};
  acc[0] += snv * h0;
  acc[1] += snv * h1;
  acc[0] += *(const f2*)(bias + fl * 4);
  acc[1] += *(const f2*)(bias + fl * 4 + 2);
  if (q == 0) {
    f4 v = {acc[0][0], acc[0][1], acc[1][0], acc[1][1]};
    *(f4*)(out + (size_t)(uint32_t)wid * 64 + fl * 4) = v;
  }
}

extern "C" void kernel_launch(void* const* d_in, const int* in_sizes, int n_in,
                              void* d_out, int out_size, void* d_ws, size_t ws_size,
                              hipStream_t stream) {
  (void)in_sizes; (void)n_in; (void)out_size; (void)ws_size;
  const float* x  = (const float*)d_in[0];
  const float* W1 = (const float*)d_in[1];
  const float* b1 = (const float*)d_in[2];
  const float* W2 = (const float*)d_in[3];
  const float* b2 = (const float*)d_in[4];
  const float* W3 = (const float*)d_in[5];
  const float* b3 = (const float*)d_in[6];
  const int* ei   = (const int*)d_in[7];
  float* out = (float*)d_out;

  char* p = (char*)d_ws;
  auto alloc = [&](size_t bytes) -> void* {
    void* r = (void*)p;
    p += (bytes + 255) & ~(size_t)255;
    return r;
  };
  float*    dinv  = (float*)alloc((size_t)NN * 4);
  uint32_t* rpp   = (uint32_t*)alloc((size_t)(NN + 1) * 4);
  uint32_t* bsum  = (uint32_t*)alloc(1024);
  uint32_t* bsumP = (uint32_t*)alloc(1024);
  uint2*    e2    = (uint2*)alloc((size_t)NE * 8);
  uint32_t* m1    = (uint32_t*)alloc((size_t)NMASKW * 4);
  uint32_t* m2    = (uint32_t*)alloc((size_t)NMASKW * 4);
  unsigned short* ah = (unsigned short*)alloc((size_t)NN * 128 * 2);
  unsigned short* al = (unsigned short*)alloc((size_t)NN * 128 * 2);
  unsigned short* hb = (unsigned short*)alloc((size_t)NN * 128 * 2);
  unsigned short* w1h = (unsigned short*)alloc(32 * 64 * 8 * 2);
  unsigned short* w1l = (unsigned short*)alloc(32 * 64 * 8 * 2);
  unsigned short* w2h = (unsigned short*)alloc(32 * 64 * 8 * 2);
  unsigned short* w2l = (unsigned short*)alloc(32 * 64 * 8 * 2);
  unsigned short* w3h = (unsigned short*)alloc(16 * 64 * 8 * 2);
  unsigned short* w3l = (unsigned short*)alloc(16 * 64 * 8 * 2);

  // hc (per-chunk hist) and cp (chunk prefix) alias ah/al: both are dead
  // before agg_mid first writes ah/al.
  unsigned short* hc = ah;  // [NCHUNK][NN] u16 = 12.8 MB <= 25.6 MB
  unsigned short* cp = al;  // [NCHUNK][NN] u16

  // JAX: kd1, kd2 = split(key(42)) — partitionable/fold-like split.
  uint32_t kd1a, kd1b, kd2a, kd2b;
  threefry2x32(0u, 42u, 0u, 0u, &kd1a, &kd1b);
  threefry2x32(0u, 42u, 0u, 1u, &kd2a, &kd2b);

  const int gbScan = (NN + 1023) / 1024;  // 98
  const int gbGemm = (NN + 127) / 128;    // 782 (32 rows/wave)
  const int gbAgg = (NN + 3) / 4;

  k_hist_lds<<<NRANGE * NCHUNK, 1024, 0, stream>>>(ei, hc);
  k_maskwsplit<<<WSPL_BLKS + MASK_BLKS, 256, 0, stream>>>(
      m1, m2, kd1a, kd1b, kd2a, kd2b, W1, W2, W3,
      w1h, w1l, w2h, w2l, w3h, w3l);
  k_scan1<<<gbScan, 256, 0, stream>>>(hc, cp, rpp, bsum, dinv);
  k_scan2<<<1, 128, 0, stream>>>(bsum, bsumP, rpp, gbScan);
  k_scat_lds<<<NRANGE * NCHUNK, 1024, 0, stream>>>(ei, rpp, bsumP, cp, dinv, e2);

  k_gemm1<<<gbGemm, 256, 0, stream>>>(x, w1h, w1l, hb);
  k_agg_mid<<<gbAgg, 256, 0, stream>>>(hb, rpp, bsumP, e2, dinv, b1, m1, ah, al);
  k_gemm_mfma<128><<<gbGemm, 256, 0, stream>>>(ah, al, w2h, w2l, hb);
  k_agg_mid<<<gbAgg, 256, 0, stream>>>(hb, rpp, bsumP, e2, dinv, b2, m2, ah, al);
  k_gemm_mfma<64><<<gbGemm, 256, 0, stream>>>(ah, al, w3h, w3l, hb);
  k_agg_final<<<gbAgg, 256, 0, stream>>>(hb, rpp, bsumP, e2, dinv, b3, out);
}